// Round 1
// baseline (102.451 us; speedup 1.0000x reference)
//
#include <hip/hip_runtime.h>
#include <hip/hip_bf16.h>

// TT embedding: cores
//   core0: (1, 8, 40, 16)   [a, x, p, b]
//   core1: (16, 8, 32, 16)  [b, y, q, c]
//   core2: (16, 16, 25, 1)  [c, z, r, d]
// out[t, e] with e = (x*8+y)*16+z, token id v -> p=v/800, q=(v/25)%32, r=v%25
//
// Strategy: precompute T12[p][q][c][xy] = sum_b core0[x,p,b]*core1[b,y,q,c]
// (40*32*16*64 = 1,310,720 floats = 5.2 MB in d_ws) and C2T[r][c][z]
// (25*16*16 = 6400 floats). Gather kernel: one wave per token, lane computes
// a 4x4 (xy x z) tile via outer product over c (32 dwordx4 loads, 256 FMA).

#define T12_FLOATS (40 * 32 * 16 * 64)
#define C2T_FLOATS (25 * 16 * 16)

__global__ __launch_bounds__(256) void tt_precompute_kernel(
    const float* __restrict__ core0, const float* __restrict__ core1,
    const float* __restrict__ core2, float* __restrict__ T12,
    float* __restrict__ C2T) {
  if (blockIdx.x == 1280) {
    // transpose core2 -> C2T[r*256 + c*16 + z] = core2[(c*16+z)*25 + r]
    for (int i = threadIdx.x; i < C2T_FLOATS; i += 256) {
      int r = i >> 8;        // i / 256
      int cz = i & 255;      // c*16+z
      C2T[i] = core2[cz * 25 + r];
    }
    return;
  }
  int pq = blockIdx.x;  // 0..1279
  int p = pq >> 5;      // / 32
  int q = pq & 31;

  __shared__ float sA[8 * 16];        // core0[x][b] at this p
  __shared__ float sB[16 * 8 * 16];   // core1[b][y][c] at this q

  for (int i = threadIdx.x; i < 128; i += 256) {
    int x = i >> 4, b = i & 15;
    sA[i] = core0[(x * 40 + p) * 16 + b];
  }
  for (int i = threadIdx.x; i < 2048; i += 256) {
    int b = i >> 7;        // / 128
    int yc = i & 127;      // y*16+c
    int y = yc >> 4, c = yc & 15;
    sB[i] = core1[((b * 8 + y) * 32 + q) * 16 + c];
  }
  __syncthreads();

  // 1024 outputs per (p,q): layout dst[c*64 + xy]; 256 threads -> 4 c each
  float* dst = T12 + pq * 1024;
  int xy = threadIdx.x & 63;
  int x = xy >> 3, y = xy & 7;
  for (int c = threadIdx.x >> 6; c < 16; c += 4) {
    float acc = 0.f;
#pragma unroll
    for (int b = 0; b < 16; b++) acc += sA[x * 16 + b] * sB[b * 128 + y * 16 + c];
    dst[c * 64 + xy] = acc;
  }
}

__global__ __launch_bounds__(256) void tt_gather_kernel(
    const float* __restrict__ T12, const float* __restrict__ C2T,
    const int* __restrict__ ids, float* __restrict__ out) {
  int wave = threadIdx.x >> 6;
  int lane = threadIdx.x & 63;
  int t = blockIdx.x * 4 + wave;  // token index, grid exactly covers 16384

  int id = ids[t];
  int p = id / 800;
  int rem = id - p * 800;
  int q = rem / 25;
  int r = rem - q * 25;

  const float4* E = (const float4*)(T12 + (p * 32 + q) * 1024);  // [c][xy/4]: 16x16 float4
  const float4* C = (const float4*)(C2T + r * 256);              // [c][z/4] : 16x4  float4

  int xyg = lane >> 2;  // 0..15 : xy in [xyg*4, xyg*4+4)
  int zg = lane & 3;    // 0..3  : z  in [zg*4,  zg*4+4)

  float acc[4][4];
#pragma unroll
  for (int i = 0; i < 4; i++)
#pragma unroll
    for (int j = 0; j < 4; j++) acc[i][j] = 0.f;

#pragma unroll
  for (int c = 0; c < 16; c++) {
    float4 e4 = E[c * 16 + xyg];  // E[c][xyg*4 .. +3], 256B coalesced, 4-way bcast
    float4 w4 = C[c * 4 + zg];    // C[c][zg*4 .. +3], 64B, 16-way bcast
    float ev[4] = {e4.x, e4.y, e4.z, e4.w};
    float wv[4] = {w4.x, w4.y, w4.z, w4.w};
#pragma unroll
    for (int i = 0; i < 4; i++)
#pragma unroll
      for (int j = 0; j < 4; j++) acc[i][j] += ev[i] * wv[j];
  }

  // out[t*1024 + xy*16 + z], xy = xyg*4+i, z = zg*4+j
  float* dst = out + (size_t)t * 1024 + xyg * 64 + zg * 4;
#pragma unroll
  for (int i = 0; i < 4; i++) {
    float4 v = make_float4(acc[i][0], acc[i][1], acc[i][2], acc[i][3]);
    *((float4*)(dst + i * 16)) = v;
  }
}

extern "C" void kernel_launch(void* const* d_in, const int* in_sizes, int n_in,
                              void* d_out, int out_size, void* d_ws, size_t ws_size,
                              hipStream_t stream) {
  const float* core0 = (const float*)d_in[0];
  const float* core1 = (const float*)d_in[1];
  const float* core2 = (const float*)d_in[2];
  const int* ids = (const int*)d_in[3];
  float* out = (float*)d_out;

  float* T12 = (float*)d_ws;
  float* C2T = T12 + T12_FLOATS;  // 5.24 MB + 25.6 KB total in workspace

  tt_precompute_kernel<<<dim3(1281), dim3(256), 0, stream>>>(core0, core1, core2, T12, C2T);
  tt_gather_kernel<<<dim3(16384 / 4), dim3(256), 0, stream>>>(T12, C2T, ids, out);
}